// Round 6
// baseline (2310.702 us; speedup 1.0000x reference)
//
#include <hip/hip_runtime.h>
#include <math.h>

// Problem constants (fixed by reference setup_inputs)
#define N_NODES 262144      // S*T
#define SSTMT   16384
#define TT      16
#define DD      128
#define HH      3
#define HD      384         // H*D
#define EPSV    1e-5f

// ---------------------------------------------------------------------------
// 16 FMAs of one A-float4 row against 4 B-float4 rows
// ---------------------------------------------------------------------------
#define FMA16(av, b0, b1, b2, b3, ai)                                   \
    acc[ai][0] += av.x * b0.x; acc[ai][1] += av.x * b0.y;               \
    acc[ai][2] += av.x * b0.z; acc[ai][3] += av.x * b0.w;               \
    acc[ai][0] += av.y * b1.x; acc[ai][1] += av.y * b1.y;               \
    acc[ai][2] += av.y * b1.z; acc[ai][3] += av.y * b1.w;               \
    acc[ai][0] += av.z * b2.x; acc[ai][1] += av.z * b2.y;               \
    acc[ai][2] += av.z * b2.z; acc[ai][3] += av.z * b2.w;               \
    acc[ai][0] += av.w * b3.x; acc[ai][1] += av.w * b3.y;               \
    acc[ai][2] += av.w * b3.z; acc[ai][3] += av.w * b3.w;

// ---------------------------------------------------------------------------
// GEMM K=128, A from GLOBAL (row-major stride DD, half-wave broadcast reads),
// B from GLOBAL (L1/L2-resident weights, coalesced 512B per half-wave).
// acc[i][j] += A[rg*8+i][k] * B[k][c4+j]
// ---------------------------------------------------------------------------
template<int BSTR>
__device__ __forceinline__ void gemm128_gA(const float* __restrict__ Ag,
                                           const float* __restrict__ Bg,
                                           int rg, int c4, float acc[8][4])
{
    const float* ar = Ag + (size_t)(rg * 8) * DD;
    const float* bp = Bg + c4;
    #pragma unroll 4
    for (int k = 0; k < 128; k += 4) {
        float4 b0 = *reinterpret_cast<const float4*>(bp);
        float4 b1 = *reinterpret_cast<const float4*>(bp + BSTR);
        float4 b2 = *reinterpret_cast<const float4*>(bp + 2 * BSTR);
        float4 b3 = *reinterpret_cast<const float4*>(bp + 3 * BSTR);
        bp += 4 * BSTR;
        #pragma unroll
        for (int i = 0; i < 8; ++i) {
            float4 av = *reinterpret_cast<const float4*>(ar + i * DD + k);
            FMA16(av, b0, b1, b2, b3, i)
        }
    }
}

// Same but A from LDS [64][128] (half-wave broadcast ds_reads)
template<int BSTR>
__device__ __forceinline__ void gemm128_lA(const float (*A)[128],
                                           const float* __restrict__ Bg,
                                           int rg, int c4, float acc[8][4])
{
    const float* bp = Bg + c4;
    #pragma unroll 4
    for (int k = 0; k < 128; k += 4) {
        float4 b0 = *reinterpret_cast<const float4*>(bp);
        float4 b1 = *reinterpret_cast<const float4*>(bp + BSTR);
        float4 b2 = *reinterpret_cast<const float4*>(bp + 2 * BSTR);
        float4 b3 = *reinterpret_cast<const float4*>(bp + 3 * BSTR);
        bp += 4 * BSTR;
        #pragma unroll
        for (int i = 0; i < 8; ++i) {
            float4 av = *reinterpret_cast<const float4*>(&A[rg * 8 + i][k]);
            FMA16(av, b0, b1, b2, b3, i)
        }
    }
}

// ---------------------------------------------------------------------------
// attention logits + 2-edge segment softmax for a 64-row statement-aligned tile
// ---------------------------------------------------------------------------
__device__ __forceinline__ void attn64(const float (*hsv)[128],
                                       const float* avs, const float* avd,
                                       float* als, float* ald, float* aSw, float* aNw)
{
    const int tid = threadIdx.x;
    if (tid < 128) {
        int r = tid & 63;
        const float* av = (tid < 64) ? avs : avd;
        float s = 0.f;
        #pragma unroll 8
        for (int cc = 0; cc < 128; ++cc) {
            int c = (cc + r) & 127;       // 2-way bank alias max: free
            s += hsv[r][c] * av[c];
        }
        if (tid < 64) als[r] = s; else ald[r] = s;
    }
    __syncthreads();
    if (tid < 64) {
        int r = tid;
        float es = als[r] + ald[r];
        es = es > 0.f ? es : 0.2f * es;
        float aSv = 1.f, aNv = 0.f;
        if ((r & 15) != 15) {
            float en = als[r + 1] + ald[r];
            en = en > 0.f ? en : 0.2f * en;
            float m = fmaxf(es, en);
            float xse = expf(es - m), xne = expf(en - m);
            float den = xse + xne;
            aSv = xse / den; aNv = xne / den;
        }
        aSw[r] = aSv; aNw[r] = aNv;
    }
    __syncthreads();
}

// ---------------------------------------------------------------------------
// Pass 1: layer-0 forward for BN0 statistics only.
// Grid 4096 x 256 thr; 64 statement-aligned rows/block; LDS ~38KB -> 4 blk/CU.
// ---------------------------------------------------------------------------
__global__ __launch_bounds__(256, 4)
void gat0_stats(const float* __restrict__ x, const float* __restrict__ W0,
                const float* __restrict__ as0, const float* __restrict__ ad0,
                const float* __restrict__ b0, float* __restrict__ pA0)
{
    __shared__ float hs[64][128];
    __shared__ float avs[128], avd[128];
    __shared__ float als[64], ald[64], aSw[64], aNw[64];
    __shared__ float bns[8][128];

    const int tid = threadIdx.x;
    const int bid = blockIdx.x;
    const int rg = tid >> 5;          // 0..7 -> rows rg*8..rg*8+7
    const int c4 = (tid & 31) * 4;
    const size_t rb = (size_t)bid * 64;
    const float* xb = x + rb * DD;

    float psum[HH][4], qsum[HH][4];
    #pragma unroll
    for (int h = 0; h < HH; ++h)
        #pragma unroll
        for (int j = 0; j < 4; ++j) { psum[h][j] = 0.f; qsum[h][j] = 0.f; }

    for (int h = 0; h < HH; ++h) {
        float acc[8][4];
        #pragma unroll
        for (int i = 0; i < 8; ++i)
            #pragma unroll
            for (int j = 0; j < 4; ++j) acc[i][j] = 0.f;

        gemm128_gA<HD>(xb, W0 + h * DD, rg, c4, acc);

        __syncthreads();                   // prior hs readers done
        #pragma unroll
        for (int i = 0; i < 8; ++i) {
            float4 v; v.x = acc[i][0]; v.y = acc[i][1]; v.z = acc[i][2]; v.w = acc[i][3];
            *reinterpret_cast<float4*>(&hs[rg * 8 + i][c4]) = v;
        }
        if (tid < 128) { avs[tid] = as0[h * DD + tid]; avd[tid] = ad0[h * DD + tid]; }
        __syncthreads();
        attn64(hs, avs, avd, als, ald, aSw, aNw);

        float4 bb = *reinterpret_cast<const float4*>(&b0[h * DD + c4]);
        #pragma unroll
        for (int i = 0; i < 8; ++i) {
            int r = rg * 8 + i;
            float4 hv = *reinterpret_cast<const float4*>(&hs[r][c4]);
            float4 hx = hv;
            if ((r & 15) != 15) hx = *reinterpret_cast<const float4*>(&hs[r + 1][c4]);
            float a_s = aSw[r], a_n = aNw[r];
            float o0 = fmaxf(a_s * hv.x + a_n * hx.x + bb.x, 0.f);
            float o1 = fmaxf(a_s * hv.y + a_n * hx.y + bb.y, 0.f);
            float o2 = fmaxf(a_s * hv.z + a_n * hx.z + bb.z, 0.f);
            float o3 = fmaxf(a_s * hv.w + a_n * hx.w + bb.w, 0.f);
            psum[h][0] += o0; qsum[h][0] += o0 * o0;
            psum[h][1] += o1; qsum[h][1] += o1 * o1;
            psum[h][2] += o2; qsum[h][2] += o2 * o2;
            psum[h][3] += o3; qsum[h][3] += o3 * o3;
        }
    }

    // flush BN0 partials per head
    for (int h = 0; h < HH; ++h) {
        __syncthreads();
        #pragma unroll
        for (int j = 0; j < 4; ++j) {
            float s = psum[h][j] + __shfl_down(psum[h][j], 32);
            float q = qsum[h][j] + __shfl_down(qsum[h][j], 32);
            if ((tid & 63) < 32) {
                int w = tid >> 6;
                bns[w][c4 + j] = s;
                bns[4 + w][c4 + j] = q;
            }
        }
        __syncthreads();
        if (tid < 128) {
            float s = bns[0][tid] + bns[1][tid] + bns[2][tid] + bns[3][tid];
            float q = bns[4][tid] + bns[5][tid] + bns[6][tid] + bns[7][tid];
            size_t idx = ((size_t)bid * HD + h * DD + tid) * 2;
            pA0[idx] = s; pA0[idx + 1] = q;
        }
    }
}

// ---------------------------------------------------------------------------
// Pass 3: recompute layer-0 (BN0 applied), interleaved layer-1 GEMM per head,
// layer-1 attention, write r1 + BN1 partials. 64 rows/block, LDS ~38KB.
// ---------------------------------------------------------------------------
__global__ __launch_bounds__(256, 4)
void gat1_recomp(const float* __restrict__ x, const float* __restrict__ W0,
                 const float* __restrict__ as0, const float* __restrict__ ad0,
                 const float* __restrict__ b0, const float* __restrict__ sc0,
                 const float* __restrict__ sh0, const float* __restrict__ W1,
                 const float* __restrict__ as1, const float* __restrict__ ad1,
                 const float* __restrict__ b1,
                 float* __restrict__ r1, float* __restrict__ pA1)
{
    __shared__ float hs[64][128];
    __shared__ float avs[128], avd[128];
    __shared__ float als[64], ald[64], aSw[64], aNw[64];
    __shared__ float bns[8][128];

    const int tid = threadIdx.x;
    const int bid = blockIdx.x;
    const int rg = tid >> 5;
    const int c4 = (tid & 31) * 4;
    const size_t rb = (size_t)bid * 64;
    const float* xb = x + rb * DD;

    float acc2[8][4];                      // layer-1 accumulator (K=384)
    #pragma unroll
    for (int i = 0; i < 8; ++i)
        #pragma unroll
        for (int j = 0; j < 4; ++j) acc2[i][j] = 0.f;

    for (int h = 0; h < HH; ++h) {
        // ---- layer-0 GEMM for head h (A from global x, B from global W0) ----
        float acc[8][4];
        #pragma unroll
        for (int i = 0; i < 8; ++i)
            #pragma unroll
            for (int j = 0; j < 4; ++j) acc[i][j] = 0.f;

        gemm128_gA<HD>(xb, W0 + h * DD, rg, c4, acc);

        __syncthreads();                   // prev head's GEMM1 reads of hs done
        #pragma unroll
        for (int i = 0; i < 8; ++i) {
            float4 v; v.x = acc[i][0]; v.y = acc[i][1]; v.z = acc[i][2]; v.w = acc[i][3];
            *reinterpret_cast<float4*>(&hs[rg * 8 + i][c4]) = v;
        }
        if (tid < 128) { avs[tid] = as0[h * DD + tid]; avd[tid] = ad0[h * DD + tid]; }
        __syncthreads();
        attn64(hs, avs, avd, als, ald, aSw, aNw);

        // ---- aggregate + b0 + relu + BN0 -> regs ----
        float4 bb  = *reinterpret_cast<const float4*>(&b0[h * DD + c4]);
        float4 scv = *reinterpret_cast<const float4*>(&sc0[h * DD + c4]);
        float4 shv = *reinterpret_cast<const float4*>(&sh0[h * DD + c4]);
        float rr[8][4];
        #pragma unroll
        for (int i = 0; i < 8; ++i) {
            int r = rg * 8 + i;
            float4 hv = *reinterpret_cast<const float4*>(&hs[r][c4]);
            float4 hx = hv;
            if ((r & 15) != 15) hx = *reinterpret_cast<const float4*>(&hs[r + 1][c4]);
            float a_s = aSw[r], a_n = aNw[r];
            rr[i][0] = fmaxf(a_s * hv.x + a_n * hx.x + bb.x, 0.f) * scv.x + shv.x;
            rr[i][1] = fmaxf(a_s * hv.y + a_n * hx.y + bb.y, 0.f) * scv.y + shv.y;
            rr[i][2] = fmaxf(a_s * hv.z + a_n * hx.z + bb.z, 0.f) * scv.z + shv.z;
            rr[i][3] = fmaxf(a_s * hv.w + a_n * hx.w + bb.w, 0.f) * scv.w + shv.w;
        }
        __syncthreads();                   // all reads of hs done
        #pragma unroll
        for (int i = 0; i < 8; ++i) {
            float4 v; v.x = rr[i][0]; v.y = rr[i][1]; v.z = rr[i][2]; v.w = rr[i][3];
            *reinterpret_cast<float4*>(&hs[rg * 8 + i][c4]) = v;
        }
        __syncthreads();

        // ---- layer-1 partial GEMM over k chunk [h*128, h*128+128) ----
        gemm128_lA<DD>(hs, W1 + (size_t)(h * DD) * DD, rg, c4, acc2);
    }

    // ---- layer-1 attention ----
    __syncthreads();                       // GEMM1 reads of hs done
    #pragma unroll
    for (int i = 0; i < 8; ++i) {
        float4 v; v.x = acc2[i][0]; v.y = acc2[i][1]; v.z = acc2[i][2]; v.w = acc2[i][3];
        *reinterpret_cast<float4*>(&hs[rg * 8 + i][c4]) = v;
    }
    if (tid < 128) { avs[tid] = as1[tid]; avd[tid] = ad1[tid]; }
    __syncthreads();
    attn64(hs, avs, avd, als, ald, aSw, aNw);

    // aggregate + b1 + relu -> r1 + BN1 partials
    float ps1[4] = {0, 0, 0, 0}, pq1[4] = {0, 0, 0, 0};
    float4 bb1 = *reinterpret_cast<const float4*>(&b1[c4]);
    #pragma unroll
    for (int i = 0; i < 8; ++i) {
        int r = rg * 8 + i;
        float4 hv = *reinterpret_cast<const float4*>(&hs[r][c4]);
        float4 hx = hv;
        if ((r & 15) != 15) hx = *reinterpret_cast<const float4*>(&hs[r + 1][c4]);
        float a_s = aSw[r], a_n = aNw[r];
        float o0 = fmaxf(a_s * hv.x + a_n * hx.x + bb1.x, 0.f);
        float o1 = fmaxf(a_s * hv.y + a_n * hx.y + bb1.y, 0.f);
        float o2 = fmaxf(a_s * hv.z + a_n * hx.z + bb1.z, 0.f);
        float o3 = fmaxf(a_s * hv.w + a_n * hx.w + bb1.w, 0.f);
        float4 ov; ov.x = o0; ov.y = o1; ov.z = o2; ov.w = o3;
        *reinterpret_cast<float4*>(&r1[(rb + r) * DD + c4]) = ov;
        ps1[0] += o0; pq1[0] += o0 * o0;
        ps1[1] += o1; pq1[1] += o1 * o1;
        ps1[2] += o2; pq1[2] += o2 * o2;
        ps1[3] += o3; pq1[3] += o3 * o3;
    }

    __syncthreads();
    #pragma unroll
    for (int j = 0; j < 4; ++j) {
        float s = ps1[j] + __shfl_down(ps1[j], 32);
        float q = pq1[j] + __shfl_down(pq1[j], 32);
        if ((tid & 63) < 32) {
            int w = tid >> 6;
            bns[w][c4 + j] = s;
            bns[4 + w][c4 + j] = q;
        }
    }
    __syncthreads();
    if (tid < 128) {
        float s = bns[0][tid] + bns[1][tid] + bns[2][tid] + bns[3][tid];
        float q = bns[4][tid] + bns[5][tid] + bns[6][tid] + bns[7][tid];
        size_t idx = ((size_t)bid * DD + tid) * 2;
        pA1[idx] = s; pA1[idx + 1] = q;
    }
}

// ---------------------------------------------------------------------------
// BN stat reduction: per column, sum partials -> scale/shift
// ---------------------------------------------------------------------------
__global__ __launch_bounds__(256)
void bn_reduce(const float* __restrict__ pA, int nblk, int ncol, float invN,
               const float* __restrict__ g, const float* __restrict__ be,
               float* __restrict__ sc, float* __restrict__ sh)
{
    __shared__ float rs[256], rq[256];
    int col = blockIdx.x, tid = threadIdx.x;
    float s = 0.f, q = 0.f;
    for (int i = tid; i < nblk; i += 256) {
        size_t idx = ((size_t)i * ncol + col) * 2;
        s += pA[idx]; q += pA[idx + 1];
    }
    rs[tid] = s; rq[tid] = q;
    __syncthreads();
    for (int o = 128; o > 0; o >>= 1) {
        if (tid < o) { rs[tid] += rs[tid + o]; rq[tid] += rq[tid + o]; }
        __syncthreads();
    }
    if (tid == 0) {
        float mu  = rs[0] * invN;
        float var = fmaxf(rq[0] * invN - mu * mu, 0.f);
        float inv = 1.0f / sqrtf(var + EPSV);
        float scv = g[col] * inv;
        sc[col] = scv;
        sh[col] = be[col] - mu * scv;
    }
}

__global__ __launch_bounds__(128)
void compute_pn(const float* __restrict__ p, float* __restrict__ pn)
{
    __shared__ float rs[128];
    int t = threadIdx.x;
    float v = p[t];
    rs[t] = v * v;
    __syncthreads();
    for (int o = 64; o > 0; o >>= 1) {
        if (t < o) rs[t] += rs[t + o];
        __syncthreads();
    }
    float nrm = sqrtf(rs[0]) + 1e-16f;
    pn[t] = v / nrm;
}

// ---------------------------------------------------------------------------
// Pass 5: per-statement BN1 affine + score + top-8 + tanh-weighted relu mean
// + MLP 128->32->128
// ---------------------------------------------------------------------------
__global__ __launch_bounds__(128)
void pool_mlp(const float* __restrict__ r1, const float* __restrict__ sc1,
              const float* __restrict__ sh1, const float* __restrict__ pn,
              const float* __restrict__ mW1, const float* __restrict__ mb1,
              const float* __restrict__ mW2, const float* __restrict__ mb2,
              float* __restrict__ out)
{
    __shared__ float hf[16][136];
    __shared__ float sv[16];
    __shared__ float tv[16];
    __shared__ float pooled[128];
    __shared__ float y1[32];
    int tid = threadIdx.x;
    int sid = blockIdx.x;
    float scv = sc1[tid], shv = sh1[tid];
    const float* base = r1 + (size_t)sid * TT * DD;
    #pragma unroll
    for (int i = 0; i < 16; ++i)
        hf[i][tid] = base[i * DD + tid] * scv + shv;
    __syncthreads();

    {
        int r = tid >> 3, q = tid & 7;
        float s = 0.f;
        #pragma unroll
        for (int cc = 0; cc < 16; ++cc) {
            int c = q + cc * 8;
            s += hf[r][c] * pn[c];
        }
        s += __shfl_down(s, 4, 8);
        s += __shfl_down(s, 2, 8);
        s += __shfl_down(s, 1, 8);
        if (q == 0) sv[r] = s;
    }
    __syncthreads();

    if (tid < 16) {
        float si = sv[tid];
        int rank = 0;
        #pragma unroll
        for (int u = 0; u < 16; ++u) {
            float su = sv[u];
            rank += (su > si || (su == si && u < tid)) ? 1 : 0;
        }
        tv[tid] = (rank < 8) ? tanhf(si) : 0.f;
    }
    __syncthreads();

    {
        float a = 0.f;
        #pragma unroll
        for (int rr = 0; rr < 16; ++rr)
            a += fmaxf(hf[rr][tid] * tv[rr], 0.f);
        pooled[tid] = a * 0.125f;
    }
    __syncthreads();

    {
        int j = tid >> 2, q = tid & 3;
        float a = 0.f;
        #pragma unroll
        for (int cc = 0; cc < 32; ++cc) {
            int c = q + cc * 4;
            a += pooled[c] * mW1[(size_t)c * 32 + j];
        }
        a += __shfl_down(a, 2, 4);
        a += __shfl_down(a, 1, 4);
        if (q == 0) y1[j] = fmaxf(a + mb1[j], 0.f);
    }
    __syncthreads();

    {
        float o = mb2[tid];
        #pragma unroll
        for (int j = 0; j < 32; ++j) o += y1[j] * mW2[j * 128 + tid];
        out[(size_t)sid * 128 + tid] = o;
    }
}

// ===========================================================================
extern "C" void kernel_launch(void* const* d_in, const int* in_sizes, int n_in,
                              void* d_out, int out_size, void* d_ws, size_t ws_size,
                              hipStream_t stream)
{
    (void)in_sizes; (void)n_in; (void)out_size; (void)ws_size;
    const float* x   = (const float*)d_in[0];
    const float* W0  = (const float*)d_in[1];
    const float* as0 = (const float*)d_in[2];
    const float* ad0 = (const float*)d_in[3];
    const float* b0  = (const float*)d_in[4];
    const float* g0  = (const float*)d_in[5];
    const float* be0 = (const float*)d_in[6];
    const float* W1  = (const float*)d_in[7];
    const float* as1 = (const float*)d_in[8];
    const float* ad1 = (const float*)d_in[9];
    const float* b1  = (const float*)d_in[10];
    const float* g1  = (const float*)d_in[11];
    const float* be1 = (const float*)d_in[12];
    const float* p   = (const float*)d_in[13];
    const float* mW1 = (const float*)d_in[14];
    const float* mb1 = (const float*)d_in[15];
    const float* mW2 = (const float*)d_in[16];
    const float* mb2 = (const float*)d_in[17];
    float* out = (float*)d_out;

    // ws layout (~151 MB; ws >= 156 MB proven by round-2 RECOMP pass)
    const size_t R1B  = (size_t)N_NODES * DD * 4;     // 134,217,728
    const size_t PA0B = 4096ull * HD * 2 * 4;         //  12,582,912
    const size_t PA1B = 4096ull * DD * 2 * 4;         //   4,194,304

    char* ws = (char*)d_ws;
    float* r1  = (float*)ws;
    float* pA0 = (float*)(ws + R1B);
    float* pA1 = (float*)(ws + R1B + PA0B);
    float* vec = (float*)(ws + R1B + PA0B + PA1B);
    float* sc0 = vec;            // 512 floats each slot
    float* sh0 = vec + 512;
    float* sc1 = vec + 1024;
    float* sh1 = vec + 1536;
    float* pn  = vec + 2048;

    const float invN = 1.0f / (float)N_NODES;

    gat0_stats<<<N_NODES / 64, 256, 0, stream>>>(x, W0, as0, ad0, b0, pA0);
    bn_reduce<<<HD, 256, 0, stream>>>(pA0, N_NODES / 64, HD, invN, g0, be0, sc0, sh0);
    compute_pn<<<1, 128, 0, stream>>>(p, pn);
    gat1_recomp<<<N_NODES / 64, 256, 0, stream>>>(x, W0, as0, ad0, b0, sc0, sh0,
                                                  W1, as1, ad1, b1, r1, pA1);
    bn_reduce<<<DD, 256, 0, stream>>>(pA1, N_NODES / 64, DD, invN, g1, be1, sc1, sh1);
    pool_mlp<<<SSTMT, 128, 0, stream>>>(r1, sc1, sh1, pn, mW1, mb1, mW2, mb2, out);
}

// Round 7
// 1295.609 us; speedup vs baseline: 1.7835x; 1.7835x over previous
//
#include <hip/hip_runtime.h>
#include <math.h>

// Problem constants (fixed by reference setup_inputs)
#define N_NODES 262144      // S*T
#define SSTMT   16384
#define TT      16
#define DD      128
#define HH      3
#define HD      384         // H*D
#define EPSV    1e-5f

// ---------------------------------------------------------------------------
// stage a [64][128] fp32 tile row-major from global (row stride = 128 floats)
// ---------------------------------------------------------------------------
__device__ __forceinline__ void stage64x128(float (*dst)[128], const float* __restrict__ src)
{
    const int tid = threadIdx.x;
    #pragma unroll
    for (int j = 0; j < 8; ++j) {
        int gi = j * 256 + tid;          // 0..2047
        int row = gi >> 5;               // 0..63
        int col = (gi & 31) * 4;
        *reinterpret_cast<float4*>(&dst[row][col]) =
            *reinterpret_cast<const float4*>(&src[(size_t)row * DD + col]);
    }
}

// ---------------------------------------------------------------------------
// 16 FMAs of one A-float4 row against 4 B-float4 rows
// ---------------------------------------------------------------------------
#define FMA16(av, b0, b1, b2, b3, ai)                                   \
    acc[ai][0] += av.x * b0.x; acc[ai][1] += av.x * b0.y;               \
    acc[ai][2] += av.x * b0.z; acc[ai][3] += av.x * b0.w;               \
    acc[ai][0] += av.y * b1.x; acc[ai][1] += av.y * b1.y;               \
    acc[ai][2] += av.y * b1.z; acc[ai][3] += av.y * b1.w;               \
    acc[ai][0] += av.z * b2.x; acc[ai][1] += av.z * b2.y;               \
    acc[ai][2] += av.z * b2.z; acc[ai][3] += av.z * b2.w;               \
    acc[ai][0] += av.w * b3.x; acc[ai][1] += av.w * b3.y;               \
    acc[ai][2] += av.w * b3.z; acc[ai][3] += av.w * b3.w;

// ---------------------------------------------------------------------------
// GEMM K=128: acc[i][j] += A[rg*8+i][k] * B[k][c4+j]
// A: LDS [64][128] (half-wave broadcast ds_reads: conflict-free)
// B: GLOBAL (L1/L2-resident weights, coalesced 512B per half-wave)
// ---------------------------------------------------------------------------
template<int BSTR>
__device__ __forceinline__ void gemm128_lA(const float (*A)[128],
                                           const float* __restrict__ Bg,
                                           int rg, int c4, float acc[8][4])
{
    const float* bp = Bg + c4;
    #pragma unroll 4
    for (int k = 0; k < 128; k += 4) {
        float4 b0 = *reinterpret_cast<const float4*>(bp);
        float4 b1 = *reinterpret_cast<const float4*>(bp + BSTR);
        float4 b2 = *reinterpret_cast<const float4*>(bp + 2 * BSTR);
        float4 b3 = *reinterpret_cast<const float4*>(bp + 3 * BSTR);
        bp += 4 * BSTR;
        #pragma unroll
        for (int i = 0; i < 8; ++i) {
            float4 av = *reinterpret_cast<const float4*>(&A[rg * 8 + i][k]);
            FMA16(av, b0, b1, b2, b3, i)
        }
    }
}

// ---------------------------------------------------------------------------
// In-register attention for 8 rows held as acc[8][4] fragments.
// Half-wave (32 lanes, same rg) holds one row's 128 columns -> butterfly
// reduce for logits; neighbor terms via register slot / shfl_down(32).
// Within a wave: lanes 0-31 have even rg, lanes 32-63 odd rg, so row
// (rg+1)*8 data for even-rg lanes lives at lane+32.
// ---------------------------------------------------------------------------
__device__ __forceinline__ void attn_reg(const float acc[8][4],
                                         float4 av_s, float4 av_d,
                                         int rg, float aS[8], float aN[8])
{
    float als_t[8], ald_t[8];
    #pragma unroll
    for (int i = 0; i < 8; ++i) {
        als_t[i] = acc[i][0] * av_s.x + acc[i][1] * av_s.y
                 + acc[i][2] * av_s.z + acc[i][3] * av_s.w;
        ald_t[i] = acc[i][0] * av_d.x + acc[i][1] * av_d.y
                 + acc[i][2] * av_d.z + acc[i][3] * av_d.w;
    }
    #pragma unroll
    for (int m = 1; m <= 16; m <<= 1) {
        #pragma unroll
        for (int i = 0; i < 8; ++i) {
            als_t[i] += __shfl_xor(als_t[i], m);
            ald_t[i] += __shfl_xor(ald_t[i], m);
        }
    }
    float alsN = __shfl_down(als_t[0], 32);   // next rg-group row0's als (valid for even rg)
    const bool rgodd = (rg & 1);
    #pragma unroll
    for (int i = 0; i < 8; ++i) {
        float es = als_t[i] + ald_t[i];
        es = es > 0.f ? es : 0.2f * es;
        float aSv = 1.f, aNv = 0.f;
        if (!(rgodd && i == 7)) {             // statement tail rows have no neighbor
            float en = ((i < 7) ? als_t[i + 1] : alsN) + ald_t[i];
            en = en > 0.f ? en : 0.2f * en;
            float mx = fmaxf(es, en);
            float xse = expf(es - mx), xne = expf(en - mx);
            float den = xse + xne;
            aSv = xse / den; aNv = xne / den;
        }
        aS[i] = aSv; aN[i] = aNv;
    }
}

// ---------------------------------------------------------------------------
// Pass 1: layer-0 forward for BN0 statistics only.
// Grid 4096 x 256 thr; 64 statement-aligned rows/block.
// LDS = 32 KB (xs only; stats flushed through xs alias) -> 4 blocks/CU.
// Zero barriers inside the head loop.
// ---------------------------------------------------------------------------
__global__ __launch_bounds__(256, 4)
void gat0_stats(const float* __restrict__ x, const float* __restrict__ W0,
                const float* __restrict__ as0, const float* __restrict__ ad0,
                const float* __restrict__ b0, float* __restrict__ pA0)
{
    __shared__ float xs[64][128];

    const int tid = threadIdx.x;
    const int bid = blockIdx.x;
    const int rg = tid >> 5;          // 0..7 -> rows rg*8..rg*8+7
    const int c4 = (tid & 31) * 4;
    const size_t rb = (size_t)bid * 64;

    stage64x128(xs, x + rb * DD);
    __syncthreads();

    float psum[HH][4], qsum[HH][4];
    #pragma unroll
    for (int h = 0; h < HH; ++h)
        #pragma unroll
        for (int j = 0; j < 4; ++j) { psum[h][j] = 0.f; qsum[h][j] = 0.f; }

    for (int h = 0; h < HH; ++h) {
        float acc[8][4];
        #pragma unroll
        for (int i = 0; i < 8; ++i)
            #pragma unroll
            for (int j = 0; j < 4; ++j) acc[i][j] = 0.f;

        gemm128_lA<HD>(xs, W0 + h * DD, rg, c4, acc);

        float4 avS = *reinterpret_cast<const float4*>(&as0[h * DD + c4]);
        float4 avD = *reinterpret_cast<const float4*>(&ad0[h * DD + c4]);
        float aS[8], aN[8];
        attn_reg(acc, avS, avD, rg, aS, aN);

        float accN[4];
        #pragma unroll
        for (int j = 0; j < 4; ++j) accN[j] = __shfl_down(acc[0][j], 32);

        float4 bb = *reinterpret_cast<const float4*>(&b0[h * DD + c4]);
        float bbv[4] = {bb.x, bb.y, bb.z, bb.w};
        const bool rgodd = (rg & 1);
        #pragma unroll
        for (int i = 0; i < 8; ++i) {
            #pragma unroll
            for (int j = 0; j < 4; ++j) {
                float nbj = (i < 7) ? acc[i + 1][j] : (rgodd ? 0.f : accN[j]);
                float o = fmaxf(aS[i] * acc[i][j] + aN[i] * nbj + bbv[j], 0.f);
                psum[h][j] += o; qsum[h][j] += o * o;
            }
        }
    }

    // flush BN0 partials through xs alias (xs dead now)
    float* bna = &xs[0][0];
    for (int h = 0; h < HH; ++h) {
        __syncthreads();
        #pragma unroll
        for (int j = 0; j < 4; ++j) {
            float s = psum[h][j] + __shfl_down(psum[h][j], 32);
            float q = qsum[h][j] + __shfl_down(qsum[h][j], 32);
            if ((tid & 63) < 32) {
                int w = tid >> 6;
                bna[w * 128 + c4 + j] = s;
                bna[512 + w * 128 + c4 + j] = q;
            }
        }
        __syncthreads();
        if (tid < 128) {
            float s = bna[tid] + bna[128 + tid] + bna[256 + tid] + bna[384 + tid];
            float q = bna[512 + tid] + bna[640 + tid] + bna[768 + tid] + bna[896 + tid];
            size_t idx = ((size_t)bid * HD + h * DD + tid) * 2;
            pA0[idx] = s; pA0[idx + 1] = q;
        }
    }
}

// ---------------------------------------------------------------------------
// Pass 3: recompute layer-0 (BN0 applied, attention in regs), interleaved
// layer-1 GEMM per head, layer-1 attention in regs, write r1 + BN1 partials.
// LDS = 64 KB (xs + hs) -> 2 blocks/CU. ~9 barriers/block (vs 19 in r4).
// ---------------------------------------------------------------------------
__global__ __launch_bounds__(256, 2)
void gat1_recomp(const float* __restrict__ x, const float* __restrict__ W0,
                 const float* __restrict__ as0, const float* __restrict__ ad0,
                 const float* __restrict__ b0, const float* __restrict__ sc0,
                 const float* __restrict__ sh0, const float* __restrict__ W1,
                 const float* __restrict__ as1, const float* __restrict__ ad1,
                 const float* __restrict__ b1,
                 float* __restrict__ r1, float* __restrict__ pA1)
{
    __shared__ float xs[64][128];
    __shared__ float hs[64][128];

    const int tid = threadIdx.x;
    const int bid = blockIdx.x;
    const int rg = tid >> 5;
    const int c4 = (tid & 31) * 4;
    const size_t rb = (size_t)bid * 64;
    const bool rgodd = (rg & 1);

    stage64x128(xs, x + rb * DD);
    __syncthreads();

    float acc2[8][4];                      // layer-1 accumulator (K=384)
    #pragma unroll
    for (int i = 0; i < 8; ++i)
        #pragma unroll
        for (int j = 0; j < 4; ++j) acc2[i][j] = 0.f;

    for (int h = 0; h < HH; ++h) {
        // ---- layer-0 GEMM for head h ----
        float acc[8][4];
        #pragma unroll
        for (int i = 0; i < 8; ++i)
            #pragma unroll
            for (int j = 0; j < 4; ++j) acc[i][j] = 0.f;

        gemm128_lA<HD>(xs, W0 + h * DD, rg, c4, acc);

        // ---- in-register attention + aggregate + b0 + relu + BN0 ----
        float4 avS = *reinterpret_cast<const float4*>(&as0[h * DD + c4]);
        float4 avD = *reinterpret_cast<const float4*>(&ad0[h * DD + c4]);
        float aS[8], aN[8];
        attn_reg(acc, avS, avD, rg, aS, aN);

        float accN[4];
        #pragma unroll
        for (int j = 0; j < 4; ++j) accN[j] = __shfl_down(acc[0][j], 32);

        float4 bb  = *reinterpret_cast<const float4*>(&b0[h * DD + c4]);
        float4 scv = *reinterpret_cast<const float4*>(&sc0[h * DD + c4]);
        float4 shv = *reinterpret_cast<const float4*>(&sh0[h * DD + c4]);
        float bbv[4]  = {bb.x, bb.y, bb.z, bb.w};
        float scvv[4] = {scv.x, scv.y, scv.z, scv.w};
        float shvv[4] = {shv.x, shv.y, shv.z, shv.w};
        float rr[8][4];
        #pragma unroll
        for (int i = 0; i < 8; ++i) {
            #pragma unroll
            for (int j = 0; j < 4; ++j) {
                float nbj = (i < 7) ? acc[i + 1][j] : (rgodd ? 0.f : accN[j]);
                float o = fmaxf(aS[i] * acc[i][j] + aN[i] * nbj + bbv[j], 0.f);
                rr[i][j] = o * scvv[j] + shvv[j];
            }
        }

        __syncthreads();                   // prev head's GEMM1 readers of hs done
        #pragma unroll
        for (int i = 0; i < 8; ++i) {
            float4 v; v.x = rr[i][0]; v.y = rr[i][1]; v.z = rr[i][2]; v.w = rr[i][3];
            *reinterpret_cast<float4*>(&hs[rg * 8 + i][c4]) = v;
        }
        __syncthreads();

        // ---- layer-1 partial GEMM over k chunk [h*128, h*128+128) ----
        gemm128_lA<DD>(hs, W1 + (size_t)h * DD * DD, rg, c4, acc2);
    }

    // ---- layer-1 attention (in regs) ----
    float4 avS1 = *reinterpret_cast<const float4*>(&as1[c4]);
    float4 avD1 = *reinterpret_cast<const float4*>(&ad1[c4]);
    float aS[8], aN[8];
    attn_reg(acc2, avS1, avD1, rg, aS, aN);

    float accN[4];
    #pragma unroll
    for (int j = 0; j < 4; ++j) accN[j] = __shfl_down(acc2[0][j], 32);

    float4 bb1 = *reinterpret_cast<const float4*>(&b1[c4]);
    float bb1v[4] = {bb1.x, bb1.y, bb1.z, bb1.w};
    float ps1[4] = {0, 0, 0, 0}, pq1[4] = {0, 0, 0, 0};
    #pragma unroll
    for (int i = 0; i < 8; ++i) {
        float ov[4];
        #pragma unroll
        for (int j = 0; j < 4; ++j) {
            float nbj = (i < 7) ? acc2[i + 1][j] : (rgodd ? 0.f : accN[j]);
            float o = fmaxf(aS[i] * acc2[i][j] + aN[i] * nbj + bb1v[j], 0.f);
            ov[j] = o;
            ps1[j] += o; pq1[j] += o * o;
        }
        float4 v; v.x = ov[0]; v.y = ov[1]; v.z = ov[2]; v.w = ov[3];
        *reinterpret_cast<float4*>(&r1[(rb + rg * 8 + i) * DD + c4]) = v;
    }

    // flush BN1 partials through xs alias (xs dead)
    float* bna = &xs[0][0];
    __syncthreads();
    #pragma unroll
    for (int j = 0; j < 4; ++j) {
        float s = ps1[j] + __shfl_down(ps1[j], 32);
        float q = pq1[j] + __shfl_down(pq1[j], 32);
        if ((tid & 63) < 32) {
            int w = tid >> 6;
            bna[w * 128 + c4 + j] = s;
            bna[512 + w * 128 + c4 + j] = q;
        }
    }
    __syncthreads();
    if (tid < 128) {
        float s = bna[tid] + bna[128 + tid] + bna[256 + tid] + bna[384 + tid];
        float q = bna[512 + tid] + bna[640 + tid] + bna[768 + tid] + bna[896 + tid];
        size_t idx = ((size_t)bid * DD + tid) * 2;
        pA1[idx] = s; pA1[idx + 1] = q;
    }
}

// ---------------------------------------------------------------------------
// BN stat reduction: per column, sum partials -> scale/shift
// ---------------------------------------------------------------------------
__global__ __launch_bounds__(256)
void bn_reduce(const float* __restrict__ pA, int nblk, int ncol, float invN,
               const float* __restrict__ g, const float* __restrict__ be,
               float* __restrict__ sc, float* __restrict__ sh)
{
    __shared__ float rs[256], rq[256];
    int col = blockIdx.x, tid = threadIdx.x;
    float s = 0.f, q = 0.f;
    for (int i = tid; i < nblk; i += 256) {
        size_t idx = ((size_t)i * ncol + col) * 2;
        s += pA[idx]; q += pA[idx + 1];
    }
    rs[tid] = s; rq[tid] = q;
    __syncthreads();
    for (int o = 128; o > 0; o >>= 1) {
        if (tid < o) { rs[tid] += rs[tid + o]; rq[tid] += rq[tid + o]; }
        __syncthreads();
    }
    if (tid == 0) {
        float mu  = rs[0] * invN;
        float var = fmaxf(rq[0] * invN - mu * mu, 0.f);
        float inv = 1.0f / sqrtf(var + EPSV);
        float scv = g[col] * inv;
        sc[col] = scv;
        sh[col] = be[col] - mu * scv;
    }
}

__global__ __launch_bounds__(128)
void compute_pn(const float* __restrict__ p, float* __restrict__ pn)
{
    __shared__ float rs[128];
    int t = threadIdx.x;
    float v = p[t];
    rs[t] = v * v;
    __syncthreads();
    for (int o = 64; o > 0; o >>= 1) {
        if (t < o) rs[t] += rs[t + o];
        __syncthreads();
    }
    float nrm = sqrtf(rs[0]) + 1e-16f;
    pn[t] = v / nrm;
}

// ---------------------------------------------------------------------------
// Pass 5: per-statement BN1 affine + score + top-8 + tanh-weighted relu mean
// + MLP 128->32->128
// ---------------------------------------------------------------------------
__global__ __launch_bounds__(128)
void pool_mlp(const float* __restrict__ r1, const float* __restrict__ sc1,
              const float* __restrict__ sh1, const float* __restrict__ pn,
              const float* __restrict__ mW1, const float* __restrict__ mb1,
              const float* __restrict__ mW2, const float* __restrict__ mb2,
              float* __restrict__ out)
{
    __shared__ float hf[16][136];
    __shared__ float sv[16];
    __shared__ float tv[16];
    __shared__ float pooled[128];
    __shared__ float y1[32];
    int tid = threadIdx.x;
    int sid = blockIdx.x;
    float scv = sc1[tid], shv = sh1[tid];
    const float* base = r1 + (size_t)sid * TT * DD;
    #pragma unroll
    for (int i = 0; i < 16; ++i)
        hf[i][tid] = base[i * DD + tid] * scv + shv;
    __syncthreads();

    {
        int r = tid >> 3, q = tid & 7;
        float s = 0.f;
        #pragma unroll
        for (int cc = 0; cc < 16; ++cc) {
            int c = q + cc * 8;
            s += hf[r][c] * pn[c];
        }
        s += __shfl_down(s, 4, 8);
        s += __shfl_down(s, 2, 8);
        s += __shfl_down(s, 1, 8);
        if (q == 0) sv[r] = s;
    }
    __syncthreads();

    if (tid < 16) {
        float si = sv[tid];
        int rank = 0;
        #pragma unroll
        for (int u = 0; u < 16; ++u) {
            float su = sv[u];
            rank += (su > si || (su == si && u < tid)) ? 1 : 0;
        }
        tv[tid] = (rank < 8) ? tanhf(si) : 0.f;
    }
    __syncthreads();

    {
        float a = 0.f;
        #pragma unroll
        for (int rr = 0; rr < 16; ++rr)
            a += fmaxf(hf[rr][tid] * tv[rr], 0.f);
        pooled[tid] = a * 0.125f;
    }
    __syncthreads();

    {
        int j = tid >> 2, q = tid & 3;
        float a = 0.f;
        #pragma unroll
        for (int cc = 0; cc < 32; ++cc) {
            int c = q + cc * 4;
            a += pooled[c] * mW1[(size_t)c * 32 + j];
        }
        a += __shfl_down(a, 2, 4);
        a += __shfl_down(a, 1, 4);
        if (q == 0) y1[j] = fmaxf(a + mb1[j], 0.f);
    }
    __syncthreads();

    {
        float o = mb2[tid];
        #pragma unroll
        for (int j = 0; j < 32; ++j) o += y1[j] * mW2[j * 128 + tid];
        out[(size_t)sid * 128 + tid] = o;
    }
}

// ===========================================================================
extern "C" void kernel_launch(void* const* d_in, const int* in_sizes, int n_in,
                              void* d_out, int out_size, void* d_ws, size_t ws_size,
                              hipStream_t stream)
{
    (void)in_sizes; (void)n_in; (void)out_size; (void)ws_size;
    const float* x   = (const float*)d_in[0];
    const float* W0  = (const float*)d_in[1];
    const float* as0 = (const float*)d_in[2];
    const float* ad0 = (const float*)d_in[3];
    const float* b0  = (const float*)d_in[4];
    const float* g0  = (const float*)d_in[5];
    const float* be0 = (const float*)d_in[6];
    const float* W1  = (const float*)d_in[7];
    const float* as1 = (const float*)d_in[8];
    const float* ad1 = (const float*)d_in[9];
    const float* b1  = (const float*)d_in[10];
    const float* g1  = (const float*)d_in[11];
    const float* be1 = (const float*)d_in[12];
    const float* p   = (const float*)d_in[13];
    const float* mW1 = (const float*)d_in[14];
    const float* mb1 = (const float*)d_in[15];
    const float* mW2 = (const float*)d_in[16];
    const float* mb2 = (const float*)d_in[17];
    float* out = (float*)d_out;

    // ws layout (~151 MB; ws >= 156 MB proven by round-2 RECOMP pass)
    const size_t R1B  = (size_t)N_NODES * DD * 4;     // 134,217,728
    const size_t PA0B = 4096ull * HD * 2 * 4;         //  12,582,912
    const size_t PA1B = 4096ull * DD * 2 * 4;         //   4,194,304

    char* ws = (char*)d_ws;
    float* r1  = (float*)ws;
    float* pA0 = (float*)(ws + R1B);
    float* pA1 = (float*)(ws + R1B + PA0B);
    float* vec = (float*)(ws + R1B + PA0B + PA1B);
    float* sc0 = vec;            // 512 floats each slot
    float* sh0 = vec + 512;
    float* sc1 = vec + 1024;
    float* sh1 = vec + 1536;
    float* pn  = vec + 2048;

    const float invN = 1.0f / (float)N_NODES;

    gat0_stats<<<N_NODES / 64, 256, 0, stream>>>(x, W0, as0, ad0, b0, pA0);
    bn_reduce<<<HD, 256, 0, stream>>>(pA0, N_NODES / 64, HD, invN, g0, be0, sc0, sh0);
    compute_pn<<<1, 128, 0, stream>>>(p, pn);
    gat1_recomp<<<N_NODES / 64, 256, 0, stream>>>(x, W0, as0, ad0, b0, sc0, sh0,
                                                  W1, as1, ad1, b1, r1, pA1);
    bn_reduce<<<DD, 256, 0, stream>>>(pA1, N_NODES / 64, DD, invN, g1, be1, sc1, sh1);
    pool_mlp<<<SSTMT, 128, 0, stream>>>(r1, sc1, sh1, pn, mW1, mb1, mW2, mb2, out);
}

// Round 8
// 1117.425 us; speedup vs baseline: 2.0679x; 1.1595x over previous
//
#include <hip/hip_runtime.h>
#include <math.h>

// Problem constants (fixed by reference setup_inputs)
#define N_NODES 262144      // S*T
#define SSTMT   16384
#define TT      16
#define DD      128
#define HH      3
#define HD      384         // H*D
#define EPSV    1e-5f

// swizzled physical column for logical 4-aligned col c in row `row`:
// spreads rows {r, r+8, r+16, r+24} across distinct 16B bank groups so the
// 4-distinct-address broadcast ds_read_b128 is conflict-free.
__device__ __forceinline__ int swzc(int row, int c) { return c ^ (((row >> 3) & 3) << 2); }

// ---------------------------------------------------------------------------
// stage a [64][128] fp32 tile from global into swizzled LDS layout
// ---------------------------------------------------------------------------
template<int NTHR>
__device__ __forceinline__ void stageSwz(float (*dst)[DD], const float* __restrict__ src)
{
    const int tid = threadIdx.x;
    #pragma unroll
    for (int j = 0; j < 2048 / NTHR; ++j) {
        int gi = j * NTHR + tid;
        int row = gi >> 5;
        int c4 = (gi & 31) * 4;
        *reinterpret_cast<float4*>(&dst[row][swzc(row, c4)]) =
            *reinterpret_cast<const float4*>(&src[(size_t)row * DD + c4]);
    }
}

// ---------------------------------------------------------------------------
// GEMM chunk: acc[i][j] += A[rr*8+i][kbeg+k] * B[kbeg+k][cg*8+j], k in [0,KLEN)
// A: swizzled LDS (broadcast b128 reads, conflict-free by swizzle)
// B: GLOBAL (Bbase already offset to column cg*8), 8 float4 loads per 4-k
// 256 FMA per 8 ds_read_b128  ->  LDS port demand 0.75 of supply
// ---------------------------------------------------------------------------
template<int BSTR, int KLEN>
__device__ __forceinline__ void gemm8x8(const float (*A)[DD], const float* __restrict__ Bbase,
                                        int kbeg, int rr, int pad, float acc[8][8])
{
    const float* bp = Bbase + (size_t)kbeg * BSTR;
    const float* ar = &A[rr * 8][0];
    #pragma unroll 2
    for (int k = 0; k < KLEN; k += 4) {
        float4 b00 = *reinterpret_cast<const float4*>(bp);
        float4 b01 = *reinterpret_cast<const float4*>(bp + 4);
        float4 b10 = *reinterpret_cast<const float4*>(bp + BSTR);
        float4 b11 = *reinterpret_cast<const float4*>(bp + BSTR + 4);
        float4 b20 = *reinterpret_cast<const float4*>(bp + 2 * BSTR);
        float4 b21 = *reinterpret_cast<const float4*>(bp + 2 * BSTR + 4);
        float4 b30 = *reinterpret_cast<const float4*>(bp + 3 * BSTR);
        float4 b31 = *reinterpret_cast<const float4*>(bp + 3 * BSTR + 4);
        bp += 4 * (size_t)BSTR;
        const int pc = (kbeg + k) ^ pad;
        #pragma unroll
        for (int i = 0; i < 8; ++i) {
            float4 a = *reinterpret_cast<const float4*>(ar + i * DD + pc);
            acc[i][0] += a.x*b00.x; acc[i][1] += a.x*b00.y; acc[i][2] += a.x*b00.z; acc[i][3] += a.x*b00.w;
            acc[i][4] += a.x*b01.x; acc[i][5] += a.x*b01.y; acc[i][6] += a.x*b01.z; acc[i][7] += a.x*b01.w;
            acc[i][0] += a.y*b10.x; acc[i][1] += a.y*b10.y; acc[i][2] += a.y*b10.z; acc[i][3] += a.y*b10.w;
            acc[i][4] += a.y*b11.x; acc[i][5] += a.y*b11.y; acc[i][6] += a.y*b11.z; acc[i][7] += a.y*b11.w;
            acc[i][0] += a.z*b20.x; acc[i][1] += a.z*b20.y; acc[i][2] += a.z*b20.z; acc[i][3] += a.z*b20.w;
            acc[i][4] += a.z*b21.x; acc[i][5] += a.z*b21.y; acc[i][6] += a.z*b21.z; acc[i][7] += a.z*b21.w;
            acc[i][0] += a.w*b30.x; acc[i][1] += a.w*b30.y; acc[i][2] += a.w*b30.z; acc[i][3] += a.w*b30.w;
            acc[i][4] += a.w*b31.x; acc[i][5] += a.w*b31.y; acc[i][6] += a.w*b31.z; acc[i][7] += a.w*b31.w;
        }
    }
}

// ---------------------------------------------------------------------------
// In-place attention + aggregation + bias + relu on acc[8][8].
// Rows rr*8..rr*8+7; logical cols cg*8..cg*8+7 spread over 16 lanes (cg).
// Logit reduce: 4-stage shfl_xor within the 16-lane group.
// Neighbor across row-groups via shfl_down(16); statement tails (rr odd, i==7)
// have no neighbor. Must be called with acc = COMBINED (full-K) values.
// ---------------------------------------------------------------------------
__device__ __forceinline__ void attnAgg(float acc[8][8],
                                        const float* __restrict__ avsP,
                                        const float* __restrict__ avdP,
                                        const float* __restrict__ bP, int rr)
{
    float4 s0 = *reinterpret_cast<const float4*>(avsP);
    float4 s1 = *reinterpret_cast<const float4*>(avsP + 4);
    float4 d0 = *reinterpret_cast<const float4*>(avdP);
    float4 d1 = *reinterpret_cast<const float4*>(avdP + 4);
    float als[8], ald[8];
    #pragma unroll
    for (int i = 0; i < 8; ++i) {
        als[i] = acc[i][0]*s0.x + acc[i][1]*s0.y + acc[i][2]*s0.z + acc[i][3]*s0.w
               + acc[i][4]*s1.x + acc[i][5]*s1.y + acc[i][6]*s1.z + acc[i][7]*s1.w;
        ald[i] = acc[i][0]*d0.x + acc[i][1]*d0.y + acc[i][2]*d0.z + acc[i][3]*d0.w
               + acc[i][4]*d1.x + acc[i][5]*d1.y + acc[i][6]*d1.z + acc[i][7]*d1.w;
    }
    #pragma unroll
    for (int m = 1; m <= 8; m <<= 1) {
        #pragma unroll
        for (int i = 0; i < 8; ++i) {
            als[i] += __shfl_xor(als[i], m);
            ald[i] += __shfl_xor(ald[i], m);
        }
    }
    float alsN = __shfl_down(als[0], 16);     // next row-group's row-0 logit
    float accN[8];
    #pragma unroll
    for (int j = 0; j < 8; ++j) accN[j] = __shfl_down(acc[0][j], 16);

    float4 bb0 = *reinterpret_cast<const float4*>(bP);
    float4 bb1 = *reinterpret_cast<const float4*>(bP + 4);
    float bbv[8] = {bb0.x, bb0.y, bb0.z, bb0.w, bb1.x, bb1.y, bb1.z, bb1.w};
    const bool tail7 = (rr & 1);              // rows rr*8+7 with rr odd are statement tails
    #pragma unroll
    for (int i = 0; i < 8; ++i) {
        float es = als[i] + ald[i];
        es = es > 0.f ? es : 0.2f * es;
        float aS = 1.f, aN = 0.f;
        if (!(tail7 && i == 7)) {
            float en = ((i < 7) ? als[i + 1] : alsN) + ald[i];
            en = en > 0.f ? en : 0.2f * en;
            float mx = fmaxf(es, en);
            float e1 = expf(es - mx), e2 = expf(en - mx);
            float den = e1 + e2;
            aS = e1 / den; aN = e2 / den;
        }
        #pragma unroll
        for (int j = 0; j < 8; ++j) {
            float nb = (i < 7) ? acc[i + 1][j] : accN[j];
            acc[i][j] = fmaxf(aS * acc[i][j] + aN * nb + bbv[j], 0.f);
        }
    }
}

// ---------------------------------------------------------------------------
// Pass 1: layer-0 forward for BN0 statistics only.
// Grid 4096 x 128 thr; 64 rows/block; 8x8 micro-tile; LDS 36KB -> 4 blk/CU.
// Zero barriers inside the head loop.
// ---------------------------------------------------------------------------
__global__ __launch_bounds__(128, 2)
void gat0_stats(const float* __restrict__ x, const float* __restrict__ W0,
                const float* __restrict__ as0, const float* __restrict__ ad0,
                const float* __restrict__ b0, float* __restrict__ pA0)
{
    __shared__ float xs[64][DD];
    __shared__ float bns[8][DD];

    const int tid = threadIdx.x;
    const int bid = blockIdx.x;
    const int rr = tid >> 4;          // 0..7 -> rows rr*8..rr*8+7
    const int cg = tid & 15;          // cols cg*8..cg*8+7
    const int pad = (rr & 3) << 2;
    const size_t rb = (size_t)bid * 64;

    stageSwz<128>(xs, x + rb * DD);
    __syncthreads();

    float psum[HH][8], qsum[HH][8];
    #pragma unroll
    for (int h = 0; h < HH; ++h)
        #pragma unroll
        for (int j = 0; j < 8; ++j) { psum[h][j] = 0.f; qsum[h][j] = 0.f; }

    for (int h = 0; h < HH; ++h) {
        float acc[8][8];
        #pragma unroll
        for (int i = 0; i < 8; ++i)
            #pragma unroll
            for (int j = 0; j < 8; ++j) acc[i][j] = 0.f;

        gemm8x8<HD, 128>(xs, W0 + h * DD + cg * 8, 0, rr, pad, acc);
        attnAgg(acc, as0 + h * DD + cg * 8, ad0 + h * DD + cg * 8, b0 + h * DD + cg * 8, rr);

        #pragma unroll
        for (int i = 0; i < 8; ++i)
            #pragma unroll
            for (int j = 0; j < 8; ++j) {
                float o = acc[i][j];
                psum[h][j] += o; qsum[h][j] += o * o;
            }
    }

    // flush BN0 partials (single 4KB buffer, two phases per head)
    for (int h = 0; h < HH; ++h) {
        __syncthreads();
        *reinterpret_cast<float4*>(&bns[rr][cg * 8]) =
            make_float4(psum[h][0], psum[h][1], psum[h][2], psum[h][3]);
        *reinterpret_cast<float4*>(&bns[rr][cg * 8 + 4]) =
            make_float4(psum[h][4], psum[h][5], psum[h][6], psum[h][7]);
        __syncthreads();
        float sv = 0.f;
        #pragma unroll
        for (int w = 0; w < 8; ++w) sv += bns[w][tid];
        __syncthreads();
        *reinterpret_cast<float4*>(&bns[rr][cg * 8]) =
            make_float4(qsum[h][0], qsum[h][1], qsum[h][2], qsum[h][3]);
        *reinterpret_cast<float4*>(&bns[rr][cg * 8 + 4]) =
            make_float4(qsum[h][4], qsum[h][5], qsum[h][6], qsum[h][7]);
        __syncthreads();
        float qv = 0.f;
        #pragma unroll
        for (int w = 0; w < 8; ++w) qv += bns[w][tid];
        size_t idx = ((size_t)bid * HD + h * DD + tid) * 2;
        pA0[idx] = sv; pA0[idx + 1] = qv;
    }
}

// ---------------------------------------------------------------------------
// Pass 3: recompute layer-0 (BN0 applied), interleaved layer-1 GEMM per head.
// Grid 4096 x 256 thr; 64 rows; 8x8 micro-tile with K-SPLIT:
//   kh = tid>>7 selects k-half [kh*64, kh*64+64); partials combined via LDS.
// LDS 72KB -> 2 blk/CU; LDS-port demand ~0.9 (vs 1.5 in round 4).
// ---------------------------------------------------------------------------
__global__ __launch_bounds__(256, 2)
void gat1_recomp(const float* __restrict__ x, const float* __restrict__ W0,
                 const float* __restrict__ as0, const float* __restrict__ ad0,
                 const float* __restrict__ b0, const float* __restrict__ sc0,
                 const float* __restrict__ sh0, const float* __restrict__ W1,
                 const float* __restrict__ as1, const float* __restrict__ ad1,
                 const float* __restrict__ b1,
                 float* __restrict__ r1, float* __restrict__ pA1)
{
    __shared__ float xs[64][DD];
    __shared__ float hs[64][DD];
    __shared__ float bps[8][DD], bqs[8][DD];

    const int tid = threadIdx.x;
    const int bid = blockIdx.x;
    const int kh = tid >> 7;          // k-half
    const int rr = (tid >> 4) & 7;
    const int cg = tid & 15;
    const int pad = (rr & 3) << 2;
    const size_t rb = (size_t)bid * 64;

    stageSwz<256>(xs, x + rb * DD);
    __syncthreads();

    float acc2[8][8];                 // layer-1 partial accumulator (this k-half)
    #pragma unroll
    for (int i = 0; i < 8; ++i)
        #pragma unroll
        for (int j = 0; j < 8; ++j) acc2[i][j] = 0.f;

    for (int h = 0; h < HH; ++h) {
        // ---- layer-0 GEMM for head h (this thread's k-half) ----
        float acc[8][8];
        #pragma unroll
        for (int i = 0; i < 8; ++i)
            #pragma unroll
            for (int j = 0; j < 8; ++j) acc[i][j] = 0.f;

        gemm8x8<HD, 64>(xs, W0 + h * DD + cg * 8, kh * 64, rr, pad, acc);

        __syncthreads();              // prev head's GEMM1 hs-readers done
        if (kh == 1) {
            #pragma unroll
            for (int i = 0; i < 8; ++i) {
                int pc = (cg * 8) ^ pad;
                *reinterpret_cast<float4*>(&hs[rr * 8 + i][pc]) =
                    make_float4(acc[i][0], acc[i][1], acc[i][2], acc[i][3]);
                *reinterpret_cast<float4*>(&hs[rr * 8 + i][pc ^ 4]) =
                    make_float4(acc[i][4], acc[i][5], acc[i][6], acc[i][7]);
            }
        }
        __syncthreads();
        if (kh == 0) {
            // combine k-halves
            #pragma unroll
            for (int i = 0; i < 8; ++i) {
                int pc = (cg * 8) ^ pad;
                float4 p0 = *reinterpret_cast<const float4*>(&hs[rr * 8 + i][pc]);
                float4 p1 = *reinterpret_cast<const float4*>(&hs[rr * 8 + i][pc ^ 4]);
                acc[i][0] += p0.x; acc[i][1] += p0.y; acc[i][2] += p0.z; acc[i][3] += p0.w;
                acc[i][4] += p1.x; acc[i][5] += p1.y; acc[i][6] += p1.z; acc[i][7] += p1.w;
            }
            attnAgg(acc, as0 + h * DD + cg * 8, ad0 + h * DD + cg * 8, b0 + h * DD + cg * 8, rr);
            // BN0 apply
            float4 sc0a = *reinterpret_cast<const float4*>(&sc0[h * DD + cg * 8]);
            float4 sc0b = *reinterpret_cast<const float4*>(&sc0[h * DD + cg * 8 + 4]);
            float4 sh0a = *reinterpret_cast<const float4*>(&sh0[h * DD + cg * 8]);
            float4 sh0b = *reinterpret_cast<const float4*>(&sh0[h * DD + cg * 8 + 4]);
            float scv[8] = {sc0a.x, sc0a.y, sc0a.z, sc0a.w, sc0b.x, sc0b.y, sc0b.z, sc0b.w};
            float shv[8] = {sh0a.x, sh0a.y, sh0a.z, sh0a.w, sh0b.x, sh0b.y, sh0b.z, sh0b.w};
            #pragma unroll
            for (int i = 0; i < 8; ++i) {
                int pc = (cg * 8) ^ pad;
                float v0 = acc[i][0] * scv[0] + shv[0];
                float v1 = acc[i][1] * scv[1] + shv[1];
                float v2 = acc[i][2] * scv[2] + shv[2];
                float v3 = acc[i][3] * scv[3] + shv[3];
                float v4 = acc[i][4] * scv[4] + shv[4];
                float v5 = acc[i][5] * scv[5] + shv[5];
                float v6 = acc[i][6] * scv[6] + shv[6];
                float v7 = acc[i][7] * scv[7] + shv[7];
                *reinterpret_cast<float4*>(&hs[rr * 8 + i][pc]) = make_float4(v0, v1, v2, v3);
                *reinterpret_cast<float4*>(&hs[rr * 8 + i][pc ^ 4]) = make_float4(v4, v5, v6, v7);
            }
        }
        __syncthreads();

        // ---- layer-1 partial GEMM over this k-half of hs ----
        gemm8x8<DD, 64>(hs, W1 + (size_t)(h * DD) * DD + cg * 8, kh * 64, rr, pad, acc2);
    }

    // ---- combine acc2 halves via xs (dead), layer-1 attention, outputs ----
    __syncthreads();
    if (kh == 1) {
        #pragma unroll
        for (int i = 0; i < 8; ++i) {
            int pc = (cg * 8) ^ pad;
            *reinterpret_cast<float4*>(&xs[rr * 8 + i][pc]) =
                make_float4(acc2[i][0], acc2[i][1], acc2[i][2], acc2[i][3]);
            *reinterpret_cast<float4*>(&xs[rr * 8 + i][pc ^ 4]) =
                make_float4(acc2[i][4], acc2[i][5], acc2[i][6], acc2[i][7]);
        }
    }
    __syncthreads();
    if (kh == 0) {
        #pragma unroll
        for (int i = 0; i < 8; ++i) {
            int pc = (cg * 8) ^ pad;
            float4 p0 = *reinterpret_cast<const float4*>(&xs[rr * 8 + i][pc]);
            float4 p1 = *reinterpret_cast<const float4*>(&xs[rr * 8 + i][pc ^ 4]);
            acc2[i][0] += p0.x; acc2[i][1] += p0.y; acc2[i][2] += p0.z; acc2[i][3] += p0.w;
            acc2[i][4] += p1.x; acc2[i][5] += p1.y; acc2[i][6] += p1.z; acc2[i][7] += p1.w;
        }
        attnAgg(acc2, as1 + cg * 8, ad1 + cg * 8, b1 + cg * 8, rr);

        float ps[8], pq[8];
        #pragma unroll
        for (int j = 0; j < 8; ++j) { ps[j] = 0.f; pq[j] = 0.f; }
        #pragma unroll
        for (int i = 0; i < 8; ++i) {
            *reinterpret_cast<float4*>(&r1[(rb + rr * 8 + i) * DD + cg * 8]) =
                make_float4(acc2[i][0], acc2[i][1], acc2[i][2], acc2[i][3]);
            *reinterpret_cast<float4*>(&r1[(rb + rr * 8 + i) * DD + cg * 8 + 4]) =
                make_float4(acc2[i][4], acc2[i][5], acc2[i][6], acc2[i][7]);
            #pragma unroll
            for (int j = 0; j < 8; ++j) { ps[j] += acc2[i][j]; pq[j] += acc2[i][j] * acc2[i][j]; }
        }
        *reinterpret_cast<float4*>(&bps[rr][cg * 8])     = make_float4(ps[0], ps[1], ps[2], ps[3]);
        *reinterpret_cast<float4*>(&bps[rr][cg * 8 + 4]) = make_float4(ps[4], ps[5], ps[6], ps[7]);
        *reinterpret_cast<float4*>(&bqs[rr][cg * 8])     = make_float4(pq[0], pq[1], pq[2], pq[3]);
        *reinterpret_cast<float4*>(&bqs[rr][cg * 8 + 4]) = make_float4(pq[4], pq[5], pq[6], pq[7]);
    }
    __syncthreads();
    if (tid < 128) {
        float s = 0.f, q = 0.f;
        #pragma unroll
        for (int w = 0; w < 8; ++w) { s += bps[w][tid]; q += bqs[w][tid]; }
        size_t idx = ((size_t)bid * DD + tid) * 2;
        pA1[idx] = s; pA1[idx + 1] = q;
    }
}

// ---------------------------------------------------------------------------
// BN stat reduction: per column, sum partials -> scale/shift
// ---------------------------------------------------------------------------
__global__ __launch_bounds__(256)
void bn_reduce(const float* __restrict__ pA, int nblk, int ncol, float invN,
               const float* __restrict__ g, const float* __restrict__ be,
               float* __restrict__ sc, float* __restrict__ sh)
{
    __shared__ float rs[256], rq[256];
    int col = blockIdx.x, tid = threadIdx.x;
    float s = 0.f, q = 0.f;
    for (int i = tid; i < nblk; i += 256) {
        size_t idx = ((size_t)i * ncol + col) * 2;
        s += pA[idx]; q += pA[idx + 1];
    }
    rs[tid] = s; rq[tid] = q;
    __syncthreads();
    for (int o = 128; o > 0; o >>= 1) {
        if (tid < o) { rs[tid] += rs[tid + o]; rq[tid] += rq[tid + o]; }
        __syncthreads();
    }
    if (tid == 0) {
        float mu  = rs[0] * invN;
        float var = fmaxf(rq[0] * invN - mu * mu, 0.f);
        float inv = 1.0f / sqrtf(var + EPSV);
        float scv = g[col] * inv;
        sc[col] = scv;
        sh[col] = be[col] - mu * scv;
    }
}

__global__ __launch_bounds__(128)
void compute_pn(const float* __restrict__ p, float* __restrict__ pn)
{
    __shared__ float rs[128];
    int t = threadIdx.x;
    float v = p[t];
    rs[t] = v * v;
    __syncthreads();
    for (int o = 64; o > 0; o >>= 1) {
        if (t < o) rs[t] += rs[t + o];
        __syncthreads();
    }
    float nrm = sqrtf(rs[0]) + 1e-16f;
    pn[t] = v / nrm;
}

// ---------------------------------------------------------------------------
// Pass 5: per-statement BN1 affine + score + top-8 + tanh-weighted relu mean
// + MLP 128->32->128
// ---------------------------------------------------------------------------
__global__ __launch_bounds__(128)
void pool_mlp(const float* __restrict__ r1, const float* __restrict__ sc1,
              const float* __restrict__ sh1, const float* __restrict__ pn,
              const float* __restrict__ mW1, const float* __restrict__ mb1,
              const float* __restrict__ mW2, const float* __restrict__ mb2,
              float* __restrict__ out)
{
    __shared__ float hf[16][136];
    __shared__ float sv[16];
    __shared__ float tv[16];
    __shared__ float pooled[128];
    __shared__ float y1[32];
    int tid = threadIdx.x;
    int sid = blockIdx.x;
    float scv = sc1[tid], shv = sh1[tid];
    const float* base = r1 + (size_t)sid * TT * DD;
    #pragma unroll
    for (int i = 0; i < 16; ++i)
        hf[i][tid] = base[i * DD + tid] * scv + shv;
    __syncthreads();

    {
        int r = tid >> 3, q = tid & 7;
        float s = 0.f;
        #pragma unroll
        for (int cc = 0; cc < 16; ++cc) {
            int c = q + cc * 8;
            s += hf[r][c] * pn[c];
        }
        s += __shfl_down(s, 4, 8);
        s += __shfl_down(s, 2, 8);
        s += __shfl_down(s, 1, 8);
        if (q == 0) sv[r] = s;
    }
    __syncthreads();

    if (tid < 16) {
        float si = sv[tid];
        int rank = 0;
        #pragma unroll
        for (int u = 0; u < 16; ++u) {
            float su = sv[u];
            rank += (su > si || (su == si && u < tid)) ? 1 : 0;
        }
        tv[tid] = (rank < 8) ? tanhf(si) : 0.f;
    }
    __syncthreads();

    {
        float a = 0.f;
        #pragma unroll
        for (int rr2 = 0; rr2 < 16; ++rr2)
            a += fmaxf(hf[rr2][tid] * tv[rr2], 0.f);
        pooled[tid] = a * 0.125f;
    }
    __syncthreads();

    {
        int j = tid >> 2, q = tid & 3;
        float a = 0.f;
        #pragma unroll
        for (int cc = 0; cc < 32; ++cc) {
            int c = q + cc * 4;
            a += pooled[c] * mW1[(size_t)c * 32 + j];
        }
        a += __shfl_down(a, 2, 4);
        a += __shfl_down(a, 1, 4);
        if (q == 0) y1[j] = fmaxf(a + mb1[j], 0.f);
    }
    __syncthreads();

    {
        float o = mb2[tid];
        #pragma unroll
        for (int j = 0; j < 32; ++j) o += y1[j] * mW2[j * 128 + tid];
        out[(size_t)sid * 128 + tid] = o;
    }
}

// ===========================================================================
extern "C" void kernel_launch(void* const* d_in, const int* in_sizes, int n_in,
                              void* d_out, int out_size, void* d_ws, size_t ws_size,
                              hipStream_t stream)
{
    (void)in_sizes; (void)n_in; (void)out_size; (void)ws_size;
    const float* x   = (const float*)d_in[0];
    const float* W0  = (const float*)d_in[1];
    const float* as0 = (const float*)d_in[2];
    const float* ad0 = (const float*)d_in[3];
    const float* b0  = (const float*)d_in[4];
    const float* g0  = (const float*)d_in[5];
    const float* be0 = (const float*)d_in[6];
    const float* W1  = (const float*)d_in[7];
    const float* as1 = (const float*)d_in[8];
    const float* ad1 = (const float*)d_in[9];
    const float* b1  = (const float*)d_in[10];
    const float* g1  = (const float*)d_in[11];
    const float* be1 = (const float*)d_in[12];
    const float* p   = (const float*)d_in[13];
    const float* mW1 = (const float*)d_in[14];
    const float* mb1 = (const float*)d_in[15];
    const float* mW2 = (const float*)d_in[16];
    const float* mb2 = (const float*)d_in[17];
    float* out = (float*)d_out;

    // ws layout (~151 MB; ws >= 156 MB proven by round-2 RECOMP pass)
    const size_t R1B  = (size_t)N_NODES * DD * 4;     // 134,217,728
    const size_t PA0B = 4096ull * HD * 2 * 4;         //  12,582,912
    const size_t PA1B = 4096ull * DD * 2 * 4;         //   4,194,304

    char* ws = (char*)d_ws;
    float* r1  = (float*)ws;
    float* pA0 = (float*)(ws + R1B);
    float* pA1 = (float*)(ws + R1B + PA0B);
    float* vec = (float*)(ws + R1B + PA0B + PA1B);
    float* sc0 = vec;            // 512 floats each slot
    float* sh0 = vec + 512;
    float* sc1 = vec + 1024;
    float* sh1 = vec + 1536;
    float* pn  = vec + 2048;

    const float invN = 1.0f / (float)N_NODES;

    gat0_stats<<<N_NODES / 64, 128, 0, stream>>>(x, W0, as0, ad0, b0, pA0);
    bn_reduce<<<HD, 256, 0, stream>>>(pA0, N_NODES / 64, HD, invN, g0, be0, sc0, sh0);
    compute_pn<<<1, 128, 0, stream>>>(p, pn);
    gat1_recomp<<<N_NODES / 64, 256, 0, stream>>>(x, W0, as0, ad0, b0, sc0, sh0,
                                                  W1, as1, ad1, b1, r1, pA1);
    bn_reduce<<<DD, 256, 0, stream>>>(pA1, N_NODES / 64, DD, invN, g1, be1, sc1, sh1);
    pool_mlp<<<SSTMT, 128, 0, stream>>>(r1, sc1, sh1, pn, mW1, mb1, mW2, mb2, out);
}